// Round 5
// baseline (27.175 us; speedup 1.0000x reference)
//
#include <hip/hip_runtime.h>
#include <stdint.h>

typedef unsigned int u32;

#define FW   1024
#define NOUT 50
#define RPB  4      // rows (waves) per 256-thread block
#define CAP  320    // compacted-candidate capacity (n~203, +9 sigma safe)
#define SPL  5      // slots per lane (CAP/64)

// ---- DPP helpers (ctrl must be immediate) ----
// r10 POST-MORTEM: hand-fused v_max_u32_dpp + s_nop guards was NULL (26.34 vs
// 25.88) -- the s_nops ate exactly what the fusion saved; the compiler fills
// mov_dpp hazard slots with neighboring work. Keep the builtin form.
// r11/r12 POST-MORTEM: wave phase-desync via s_sleep was a pure REGRESSION
// (+1.2us = the stagger tail). Lockstep-correlated stalls are NOT the gap;
// the kernel is latency/issue-bound (~16cy effective per loop VALU op at
// 4 waves/SIMD, from r9's slope). Only op/chain removal pays. No sleeps.
#define DPP_UMAX_STEP(m, ctrl)                                                 \
  do {                                                                         \
    const u32 _t = (u32)__builtin_amdgcn_update_dpp(0, (int)(m), (ctrl),       \
                                                    0xf, 0xf, false);          \
    (m) = (m) > _t ? (m) : _t;                                                 \
  } while (0)
#define DPP_FMAX_STEP(m, ctrl)                                                 \
  do {                                                                         \
    const float _t = __uint_as_float((u32)__builtin_amdgcn_update_dpp(         \
        __float_as_int(m), __float_as_int(m), (ctrl), 0xf, 0xf, false));       \
    (m) = fmaxf((m), _t);                                                      \
  } while (0)
#define DPP_FMIN_STEP(m, ctrl)                                                 \
  do {                                                                         \
    const float _t = __uint_as_float((u32)__builtin_amdgcn_update_dpp(         \
        __float_as_int(m), __float_as_int(m), (ctrl), 0xf, 0xf, false));       \
    (m) = fminf((m), _t);                                                      \
  } while (0)
// inclusive add-scan step; row-masked bcast steps (round-7 lesson: 0xa/0xc)
#define DPP_SCAN_STEP(x, ctrl, rmask)                                          \
  do {                                                                         \
    const int _t = __builtin_amdgcn_update_dpp(0, (x), (ctrl), (rmask), 0xf,   \
                                               false);                         \
    (x) += _t;                                                                 \
  } while (0)

#define DPP_ALL6(OP, a)                                                        \
  OP(a, 0x111); OP(a, 0x112); OP(a, 0x114); OP(a, 0x118); OP(a, 0x142);        \
  OP(a, 0x143)

__device__ __forceinline__ u32 umax2(u32 a, u32 b) { return a > b ? a : b; }
__device__ __forceinline__ u32 umax3(u32 a, u32 b, u32 c) {
  return umax2(umax2(a, b), c);   // -> v_max3_u32
}

__global__ __launch_bounds__(256, 4) void nms1d_kernel(
    const float* __restrict__ logits,
    const float* __restrict__ delta,
    const int* __restrict__ iw_p,
    float* __restrict__ out_pos,   // [B,50,2]
    float* __restrict__ out_sc)    // [B,50]
{
  const int wave = threadIdx.x >> 6;
  const int lane = threadIdx.x & 63;
  const int b = blockIdx.x * RPB + wave;

  // r13: per-wave SoA slots + 64 PER-LANE dump slots (was 1 shared dump slot:
  // ~51 invalid lanes stored float2 to the SAME LDS address on each of the 32
  // pass-2 stores; same-address WRITES may serialize (only read-broadcast is
  // proven free, m136). Distinct dump addresses cost nothing extra per elem.
  __shared__ float2 s_kc[RPB][CAP + 64];
  __shared__ float2 s_pp[RPB][CAP + 64];
  float2* __restrict__ kc = s_kc[wave];
  float2* __restrict__ pp = s_pp[wave];

  const float hi = (float)(*iw_p) - 1.0f;   // img_width - 1

  const float* __restrict__ lrow = logits + (size_t)b * FW;
  const float* __restrict__ drow = delta  + (size_t)b * FW * 2;

  // ---- batch-issue ALL global loads upfront (one latency exposure).
  float4 xl0 = *(const float4*)(lrow + lane * 16 + 0);
  float4 xl1 = *(const float4*)(lrow + lane * 16 + 4);
  float4 xl2 = *(const float4*)(lrow + lane * 16 + 8);
  float4 xl3 = *(const float4*)(lrow + lane * 16 + 12);
  float4 dA0 = *(const float4*)(drow + lane * 32 + 0);
  float4 dB0 = *(const float4*)(drow + lane * 32 + 4);
  float4 dA1 = *(const float4*)(drow + lane * 32 + 8);
  float4 dB1 = *(const float4*)(drow + lane * 32 + 12);
  float4 dA2 = *(const float4*)(drow + lane * 32 + 16);
  float4 dB2 = *(const float4*)(drow + lane * 32 + 20);
  float4 dA3 = *(const float4*)(drow + lane * 32 + 24);
  float4 dB3 = *(const float4*)(drow + lane * 32 + 28);

  // ---- pass 1: sigmoid + per-lane valid count (lane owns f = lane*16+e) ----
  float sc[16];
  int v = 0;
  const float4 xls[4] = {xl0, xl1, xl2, xl3};
#pragma unroll
  for (int c = 0; c < 4; ++c) {
    const float xs[4] = {xls[c].x, xls[c].y, xls[c].z, xls[c].w};
#pragma unroll
    for (int j = 0; j < 4; ++j) {
      const float s = 1.0f / (1.0f + expf(-xs[j]));   // frozen: bit-matched ref
      sc[c * 4 + j] = s;
      v += (s >= 0.7f) ? 1 : 0;
    }
  }

  // inclusive prefix sum over lanes via DPP (canonical masked scan, proven r8)
  int incl = v;
  DPP_SCAN_STEP(incl, 0x111, 0xf);   // row_shr:1
  DPP_SCAN_STEP(incl, 0x112, 0xf);   // row_shr:2
  DPP_SCAN_STEP(incl, 0x114, 0xf);   // row_shr:4
  DPP_SCAN_STEP(incl, 0x118, 0xf);   // row_shr:8
  DPP_SCAN_STEP(incl, 0x142, 0xa);   // row_bcast:15 -> rows 1,3 only
  DPP_SCAN_STEP(incl, 0x143, 0xc);   // row_bcast:31 -> rows 2,3 only
  const int base = incl - v;
  const int n = __builtin_amdgcn_readlane(incl, 63);

  // ---- pass 2: positions/centers, BRANCHLESS compacted scatter, vmin/vmax --
  float vmin = INFINITY, vmax = -INFINITY;
  int q = base;
  const int dumpq = CAP + lane;      // r13: per-lane dump slot
  const float4 dAs[4] = {dA0, dA1, dA2, dA3};
  const float4 dBs[4] = {dB0, dB1, dB2, dB3};
#pragma unroll
  for (int c = 0; c < 4; ++c) {
    const float dx[4] = {dAs[c].x, dAs[c].z, dBs[c].x, dBs[c].z};
    const float dy[4] = {dAs[c].y, dAs[c].w, dBs[c].y, dBs[c].w};
#pragma unroll
    for (int j = 0; j < 4; ++j) {
      const int e = c * 4 + j;
      const int f = lane * 16 + e;
      const float center = (float)f * 16.0f + 8.0f;   // (f+0.5)*16, exact
      float p0 = dx[j] * 16.0f + center;              // frozen: bit-matched ref
      float p1 = dy[j] * 16.0f + center;
      p0 = fminf(fmaxf(p0, 0.0f), hi);
      p1 = fminf(fmaxf(p1, 0.0f), hi);
      const float cc = (p0 + p1) * 0.5f;
      const float s = sc[e];
      const bool valid = (s >= 0.7f);
      vmin = valid ? fminf(vmin, cc) : vmin;          // cndmask, no exec write
      vmax = valid ? fmaxf(vmax, cc) : vmax;
      // branchless scatter: invalid (or overflow) elements hit per-lane dump
      const int qd = (valid && q < CAP) ? q : dumpq;
      // u32 key: s in [0.7,1] -> bits-diff fits 23 bits; <<9 | (511-q)
      // exact order w/ first-index tie-break (lower q = lower f).
      const u32 key = ((__float_as_uint(s) - 0x3F333333u) << 9) | (u32)(511 - q);
      kc[qd] = make_float2(__uint_as_float(key), cc);
      pp[qd] = make_float2(p0, p1);
      q += valid ? 1 : 0;
    }
  }

  // wave min/max via DPP (old=self identity; exact). Lane 63 holds the result.
  DPP_ALL6(DPP_FMIN_STEP, vmin);
  DPP_ALL6(DPP_FMAX_STEP, vmax);
  const float dt_part = (0.55f * (vmax - vmin)) / ((float)incl - 1.0f);
  const float dthresh = __uint_as_float(
      (u32)__builtin_amdgcn_readlane(__float_as_int(dt_part), 63));
  // n==1 -> NaN -> suppresses nothing (matches ref); n>=2 -> >=0 -> self-suppress

  // reload per-lane compacted slots (keys+cents) into registers (batched)
  const int nc = n < CAP ? n : CAP;
  u32 keys[SPL];
  float cents[SPL];
  {
    float2 sl[SPL];
#pragma unroll
    for (int k = 0; k < SPL; ++k) sl[k] = kc[lane * SPL + k];   // batch issue
#pragma unroll
    for (int k = 0; k < SPL; ++k) {
      const int q2 = lane * SPL + k;
      keys[k]  = (q2 < nc) ? __float_as_uint(sl[k].x) : 0u;
      cents[k] = sl[k].y;            // garbage for q2>=nc harmless (key==0)
    }
  }

  // ---- greedy NMS: 50 iters, branchless, FULLY UNROLLED ----
  // r9 POST-MORTEM (do not redo): fetching sel_c from registers via
  // cent-carrying tournament + ballot/readlane REGRESSED 25.9->29.3us.
  // Keep the 1-op uniform ds_read winner fetch.
  // r13: argmax reduce = 4 DPP scan steps (row maxima in lanes 15/31/47/63)
  // + 4 INDEPENDENT readlanes + SALU max tree. Replaces the 2 serial bcast
  // DPP pairs + readlane (5 VALU, 2 DPP-hazard windows) with 4 pipelining
  // readlanes + free-pipe scalar maxes -> shorter serial chain per iter.
  u32 acckey = 0;        // lane j: winner key of output j (0 = none)
#pragma unroll
  for (int it = 0; it < NOUT; ++it) {
    u32 m = umax3(keys[0], keys[1], keys[2]);
    m = umax3(m, keys[3], keys[4]);
    DPP_UMAX_STEP(m, 0x111);
    DPP_UMAX_STEP(m, 0x112);
    DPP_UMAX_STEP(m, 0x114);
    DPP_UMAX_STEP(m, 0x118);
    const u32 r0 = (u32)__builtin_amdgcn_readlane((int)m, 15);
    const u32 r1 = (u32)__builtin_amdgcn_readlane((int)m, 31);
    const u32 r2 = (u32)__builtin_amdgcn_readlane((int)m, 47);
    const u32 r3 = (u32)__builtin_amdgcn_readlane((int)m, 63);
    const u32 best = umax2(umax2(r0, r1), umax2(r2, r3));   // s_max_u32 tree

    // winner slot (scalar); clamp handles best==0 (keys all 0 -> harmless)
    const int qs  = 511 - (int)(best & 511u);
    const int qsc = qs < CAP ? qs : CAP - 1;
    const float sel_c = kc[qsc].y;      // uniform-addr ds_read broadcast

    // lane `it` keeps the winner key (it is a LITERAL here: v_cmp + cndmask)
    acckey = (lane == it) ? best : acckey;

    // suppress |cent - sel_c| <= dthresh (includes self -> progress)
#pragma unroll
    for (int k = 0; k < SPL; ++k) {
      keys[k] = (fabsf(cents[k] - sel_c) <= dthresh) ? 0u : keys[k];
    }
  }

  // ---- epilogue: decode acckey, fetch p0/p1, single coalesced write ----
  if (lane < NOUT) {
    float p0 = 0.0f, p1 = 0.0f, s = 0.0f;
    if (acckey != 0u) {
      const int qw = 511 - (int)(acckey & 511u);    // valid -> qw < CAP
      const float2 sl = pp[qw];
      p0 = sl.x;
      p1 = sl.y;
      s  = __uint_as_float((acckey >> 9) + 0x3F333333u);   // exact score bits
    }
    float* __restrict__ orow_p = out_pos + (size_t)b * NOUT * 2;
    float* __restrict__ orow_s = out_sc  + (size_t)b * NOUT;
    *(float2*)(orow_p + lane * 2) = make_float2(p0, p1);
    orow_s[lane] = s;
  }
}

extern "C" void kernel_launch(void* const* d_in, const int* in_sizes, int n_in,
                              void* d_out, int out_size, void* d_ws, size_t ws_size,
                              hipStream_t stream) {
  const float* logits = (const float*)d_in[0];
  const float* delta  = (const float*)d_in[1];
  const int*   iw     = (const int*)d_in[2];
  const int B = in_sizes[0] / FW;            // 4096
  float* out_pos = (float*)d_out;                         // B*50*2
  float* out_sc  = (float*)d_out + (size_t)B * NOUT * 2;  // B*50
  nms1d_kernel<<<(B + RPB - 1) / RPB, RPB * 64, 0, stream>>>(logits, delta, iw, out_pos, out_sc);
}

// Round 6
// 25.690 us; speedup vs baseline: 1.0578x; 1.0578x over previous
//
#include <hip/hip_runtime.h>
#include <stdint.h>

typedef unsigned int u32;

#define FW   1024
#define NOUT 50
#define RPB  4      // rows (waves) per 256-thread block
#define CAP  320    // compacted-candidate capacity (n~203, +9 sigma safe)
#define SPL  5      // max slots per lane (CAP/64); hot path uses 4 (n<=256)

// ---- DPP helpers (ctrl must be immediate) ----
// r10 POST-MORTEM: hand-fused v_max_u32_dpp + s_nop guards was NULL -- the
// s_nops ate exactly what the fusion saved. Keep the builtin form.
// r11/r12 POST-MORTEM: wave phase-desync via s_sleep was pure REGRESSION
// (+1.2us): lockstep-correlated stalls are NOT the gap. Latency/issue-bound.
// r13 POST-MORTEM: readlane x4 + s_max tree REGRESSED (+1.3us): 4 serial
// VALU->SALU hazard crossings beat the 2 bcast DPP pairs they replaced.
// Keep the 6-step DPP chain + single readlane(63). Per-lane dump slots
// unattributed-regressed in the same round; reverted too.
#define DPP_UMAX_STEP(m, ctrl)                                                 \
  do {                                                                         \
    const u32 _t = (u32)__builtin_amdgcn_update_dpp(0, (int)(m), (ctrl),       \
                                                    0xf, 0xf, false);          \
    (m) = (m) > _t ? (m) : _t;                                                 \
  } while (0)
#define DPP_FMAX_STEP(m, ctrl)                                                 \
  do {                                                                         \
    const float _t = __uint_as_float((u32)__builtin_amdgcn_update_dpp(         \
        __float_as_int(m), __float_as_int(m), (ctrl), 0xf, 0xf, false));       \
    (m) = fmaxf((m), _t);                                                      \
  } while (0)
#define DPP_FMIN_STEP(m, ctrl)                                                 \
  do {                                                                         \
    const float _t = __uint_as_float((u32)__builtin_amdgcn_update_dpp(         \
        __float_as_int(m), __float_as_int(m), (ctrl), 0xf, 0xf, false));       \
    (m) = fminf((m), _t);                                                      \
  } while (0)
// inclusive add-scan step; row-masked bcast steps (round-7 lesson: 0xa/0xc)
#define DPP_SCAN_STEP(x, ctrl, rmask)                                          \
  do {                                                                         \
    const int _t = __builtin_amdgcn_update_dpp(0, (x), (ctrl), (rmask), 0xf,   \
                                               false);                         \
    (x) += _t;                                                                 \
  } while (0)

#define DPP_ALL6(OP, a)                                                        \
  OP(a, 0x111); OP(a, 0x112); OP(a, 0x114); OP(a, 0x118); OP(a, 0x142);        \
  OP(a, 0x143)

__device__ __forceinline__ u32 umax2(u32 a, u32 b) { return a > b ? a : b; }
__device__ __forceinline__ u32 umax3(u32 a, u32 b, u32 c) {
  return umax2(umax2(a, b), c);   // -> v_max3_u32
}

// r14: NMS loop templated on live slot count. Candidates are distributed
// ROUND-ROBIN (slot k holds q = k*64 + lane), so slot k is entirely empty
// unless n > k*64. n ~ 203+-13 across the 4096 fixed rows => n <= 256
// essentially always => the hot path runs 4 slots (saves 3 suppress ops +
// 1 tournament op + 1 ds_read per iter vs 5). The NS=5 instantiation is the
// bit-exact cold path, selected by a WAVE-UNIFORM branch on the actual nc --
// no correctness gamble. Max/tie-break are distribution-independent (same
// key multiset; winner decode uses q embedded in the key, not the slot).
template <int NS>
__device__ __forceinline__ u32 run_nms(const float2* __restrict__ kc, int nc,
                                       int lane, float dthresh) {
  u32 keys[NS];
  float cents[NS];
  {
    float2 sl[NS];
#pragma unroll
    for (int k = 0; k < NS; ++k) sl[k] = kc[k * 64 + lane];   // batch issue
#pragma unroll
    for (int k = 0; k < NS; ++k) {
      const int q2 = k * 64 + lane;
      keys[k]  = (q2 < nc) ? __float_as_uint(sl[k].x) : 0u;
      cents[k] = sl[k].y;          // garbage for q2>=nc harmless (key==0)
    }
  }

  u32 acckey = 0;        // lane j: winner key of output j (0 = none)
#pragma unroll
  for (int it = 0; it < NOUT; ++it) {
    u32 m = umax3(keys[0], keys[1], keys[2]);
#pragma unroll
    for (int k = 3; k < NS; ++k) m = umax2(m, keys[k]);
    DPP_UMAX_STEP(m, 0x111);
    DPP_UMAX_STEP(m, 0x112);
    DPP_UMAX_STEP(m, 0x114);
    DPP_UMAX_STEP(m, 0x118);
    DPP_UMAX_STEP(m, 0x142);
    DPP_UMAX_STEP(m, 0x143);
    const u32 best = (u32)__builtin_amdgcn_readlane((int)m, 63);   // SGPR

    // winner slot (scalar); clamp handles best==0 (keys all 0 -> harmless)
    const int qs  = 511 - (int)(best & 511u);
    const int qsc = qs < CAP ? qs : CAP - 1;
    const float sel_c = kc[qsc].y;      // uniform-addr ds_read broadcast
    // r9 POST-MORTEM (do not redo): register-resident sel_c via tournament+
    // ballot REGRESSED +3.4us; the 1-op uniform ds_read is the cheap form.

    // lane `it` keeps the winner key (it is a LITERAL here: v_cmp + cndmask)
    acckey = (lane == it) ? best : acckey;

    // suppress |cent - sel_c| <= dthresh (includes self -> progress)
#pragma unroll
    for (int k = 0; k < NS; ++k) {
      keys[k] = (fabsf(cents[k] - sel_c) <= dthresh) ? 0u : keys[k];
    }
  }
  return acckey;
}

__global__ __launch_bounds__(256, 4) void nms1d_kernel(
    const float* __restrict__ logits,
    const float* __restrict__ delta,
    const int* __restrict__ iw_p,
    float* __restrict__ out_pos,   // [B,50,2]
    float* __restrict__ out_sc)    // [B,50]
{
  const int wave = threadIdx.x >> 6;
  const int lane = threadIdx.x & 63;
  const int b = blockIdx.x * RPB + wave;

  // per-wave SoA slots + 1 dump slot (branchless scatter target).
  __shared__ float2 s_kc[RPB][CAP + 1];
  __shared__ float2 s_pp[RPB][CAP + 1];
  float2* __restrict__ kc = s_kc[wave];
  float2* __restrict__ pp = s_pp[wave];

  const float hi = (float)(*iw_p) - 1.0f;   // img_width - 1

  const float* __restrict__ lrow = logits + (size_t)b * FW;
  const float* __restrict__ drow = delta  + (size_t)b * FW * 2;

  // ---- batch-issue ALL global loads upfront (one latency exposure).
  float4 xl0 = *(const float4*)(lrow + lane * 16 + 0);
  float4 xl1 = *(const float4*)(lrow + lane * 16 + 4);
  float4 xl2 = *(const float4*)(lrow + lane * 16 + 8);
  float4 xl3 = *(const float4*)(lrow + lane * 16 + 12);
  float4 dA0 = *(const float4*)(drow + lane * 32 + 0);
  float4 dB0 = *(const float4*)(drow + lane * 32 + 4);
  float4 dA1 = *(const float4*)(drow + lane * 32 + 8);
  float4 dB1 = *(const float4*)(drow + lane * 32 + 12);
  float4 dA2 = *(const float4*)(drow + lane * 32 + 16);
  float4 dB2 = *(const float4*)(drow + lane * 32 + 20);
  float4 dA3 = *(const float4*)(drow + lane * 32 + 24);
  float4 dB3 = *(const float4*)(drow + lane * 32 + 28);

  // ---- pass 1: sigmoid + per-lane valid count (lane owns f = lane*16+e) ----
  float sc[16];
  int v = 0;
  const float4 xls[4] = {xl0, xl1, xl2, xl3};
#pragma unroll
  for (int c = 0; c < 4; ++c) {
    const float xs[4] = {xls[c].x, xls[c].y, xls[c].z, xls[c].w};
#pragma unroll
    for (int j = 0; j < 4; ++j) {
      const float s = 1.0f / (1.0f + expf(-xs[j]));   // frozen: bit-matched ref
      sc[c * 4 + j] = s;
      v += (s >= 0.7f) ? 1 : 0;
    }
  }

  // inclusive prefix sum over lanes via DPP (canonical masked scan, proven r8)
  int incl = v;
  DPP_SCAN_STEP(incl, 0x111, 0xf);   // row_shr:1
  DPP_SCAN_STEP(incl, 0x112, 0xf);   // row_shr:2
  DPP_SCAN_STEP(incl, 0x114, 0xf);   // row_shr:4
  DPP_SCAN_STEP(incl, 0x118, 0xf);   // row_shr:8
  DPP_SCAN_STEP(incl, 0x142, 0xa);   // row_bcast:15 -> rows 1,3 only
  DPP_SCAN_STEP(incl, 0x143, 0xc);   // row_bcast:31 -> rows 2,3 only
  const int base = incl - v;
  const int n = __builtin_amdgcn_readlane(incl, 63);

  // ---- pass 2: positions/centers, BRANCHLESS compacted scatter, vmin/vmax --
  float vmin = INFINITY, vmax = -INFINITY;
  int q = base;
  const float4 dAs[4] = {dA0, dA1, dA2, dA3};
  const float4 dBs[4] = {dB0, dB1, dB2, dB3};
#pragma unroll
  for (int c = 0; c < 4; ++c) {
    const float dx[4] = {dAs[c].x, dAs[c].z, dBs[c].x, dBs[c].z};
    const float dy[4] = {dAs[c].y, dAs[c].w, dBs[c].y, dBs[c].w};
#pragma unroll
    for (int j = 0; j < 4; ++j) {
      const int e = c * 4 + j;
      const int f = lane * 16 + e;
      const float center = (float)f * 16.0f + 8.0f;   // (f+0.5)*16, exact
      float p0 = dx[j] * 16.0f + center;              // frozen: bit-matched ref
      float p1 = dy[j] * 16.0f + center;
      p0 = fminf(fmaxf(p0, 0.0f), hi);
      p1 = fminf(fmaxf(p1, 0.0f), hi);
      const float cc = (p0 + p1) * 0.5f;
      const float s = sc[e];
      const bool valid = (s >= 0.7f);
      vmin = valid ? fminf(vmin, cc) : vmin;          // cndmask, no exec write
      vmax = valid ? fmaxf(vmax, cc) : vmax;
      // branchless scatter: invalid (or overflow) elements hit dump slot CAP
      const int qd = (valid && q < CAP) ? q : CAP;
      // u32 key: s in [0.7,1] -> bits-diff fits 23 bits; <<9 | (511-q)
      // exact order w/ first-index tie-break (lower q = lower f).
      const u32 key = ((__float_as_uint(s) - 0x3F333333u) << 9) | (u32)(511 - q);
      kc[qd] = make_float2(__uint_as_float(key), cc);
      pp[qd] = make_float2(p0, p1);
      q += valid ? 1 : 0;
    }
  }

  // wave min/max via DPP (old=self identity; exact). Lane 63 holds the result.
  DPP_ALL6(DPP_FMIN_STEP, vmin);
  DPP_ALL6(DPP_FMAX_STEP, vmax);
  const float dt_part = (0.55f * (vmax - vmin)) / ((float)incl - 1.0f);
  const float dthresh = __uint_as_float(
      (u32)__builtin_amdgcn_readlane(__float_as_int(dt_part), 63));
  // n==1 -> NaN -> suppresses nothing (matches ref); n>=2 -> >=0 -> self-suppress

  // ---- greedy NMS: 50 iters, branchless, FULLY UNROLLED ----
  // wave-uniform dispatch on slot count (see run_nms comment).
  const int nc = n < CAP ? n : CAP;
  u32 acckey;
  if (nc <= 256) acckey = run_nms<4>(kc, nc, lane, dthresh);   // hot: ~always
  else           acckey = run_nms<5>(kc, nc, lane, dthresh);   // cold, exact

  // ---- epilogue: decode acckey, fetch p0/p1, single coalesced write ----
  if (lane < NOUT) {
    float p0 = 0.0f, p1 = 0.0f, s = 0.0f;
    if (acckey != 0u) {
      const int qw = 511 - (int)(acckey & 511u);    // valid -> qw < CAP
      const float2 sl = pp[qw];
      p0 = sl.x;
      p1 = sl.y;
      s  = __uint_as_float((acckey >> 9) + 0x3F333333u);   // exact score bits
    }
    float* __restrict__ orow_p = out_pos + (size_t)b * NOUT * 2;
    float* __restrict__ orow_s = out_sc  + (size_t)b * NOUT;
    *(float2*)(orow_p + lane * 2) = make_float2(p0, p1);
    orow_s[lane] = s;
  }
}

extern "C" void kernel_launch(void* const* d_in, const int* in_sizes, int n_in,
                              void* d_out, int out_size, void* d_ws, size_t ws_size,
                              hipStream_t stream) {
  const float* logits = (const float*)d_in[0];
  const float* delta  = (const float*)d_in[1];
  const int*   iw     = (const int*)d_in[2];
  const int B = in_sizes[0] / FW;            // 4096
  float* out_pos = (float*)d_out;                         // B*50*2
  float* out_sc  = (float*)d_out + (size_t)B * NOUT * 2;  // B*50
  nms1d_kernel<<<(B + RPB - 1) / RPB, RPB * 64, 0, stream>>>(logits, delta, iw, out_pos, out_sc);
}